// Round 2
// baseline (5000.600 us; speedup 1.0000x reference)
//
#include <hip/hip_runtime.h>
#include <math.h>

// Problem constants (B=4096, T=100, F=13, H=100)
#define B_   4096
#define T_   100
#define F_   13
#define H_   100
#define NCOL 400    // 4*H gate-columns (permuted layout, see below)
#define K0_  113    // wt0 rows: k<100 -> Whh0[.][k], 100..112 -> Wih0[.][k-100]
#define K1_  200    // wt1 rows: k<100 -> Wih1[.][k],  k>=100  -> Whh1[.][k-100]
#define CK   12     // weight chunk rows staged to LDS (double-buffered)
#define S0   116    // hT0 row stride floats: [0..99]=h0, [100..112]=x_t, [113..115]=0-pad
#define S1   200    // hT1 row stride floats: [0..99]=h0n, [100..199]=h1

// Weight column permutation p in [0,400):
//   p < 200 : cell = 2*(p/4)       (even cells), gate = p%4
//   p >= 200: cell = 2*((p-200)/4)+1 (odd cells), gate = (p-200)%4
// Thread jt (0..49) owns p in [4jt,4jt+4) and [200+4jt, 200+4jt+4): two float4
// reads that are 16B-contiguous across lanes -> conflict-free LDS reads.

// d_ws layout (bytes); total 520,896 (<= 522,432 proven available last round)
#define O_HIST   0u
#define O_ROWMAP 512u
#define O_WT0    16896u               // 113*400*4 = 180800
#define O_WT1    197696u              // 200*400*4 = 320000
#define O_B0     517696u              // 400*4
#define O_B1     519296u              // 400*4  -> end 520896

__device__ __forceinline__ float sigmoid_f(float v) {
    return 1.0f / (1.0f + __expf(-v));
}
__device__ __forceinline__ float tanh_f(float v) {
    float e = __expf(2.0f * v);
    return 1.0f - 2.0f / (e + 1.0f);
}

// ---------------- prep: counting sort of rows by length ----------------
__global__ void k_hist(const int* __restrict__ len, int* __restrict__ hist) {
    int b = blockIdx.x * blockDim.x + threadIdx.x;
    if (b < B_) atomicAdd(&hist[len[b]], 1);
}
__global__ void k_scan(int* __restrict__ hist) {
    if (threadIdx.x == 0 && blockIdx.x == 0) {
        int acc = 0;
        for (int l = 0; l <= 100; ++l) { int c = hist[l]; hist[l] = acc; acc += c; }
    }
}
__global__ void k_scatter(const int* __restrict__ len, int* __restrict__ hist,
                          int* __restrict__ rowmap) {
    int b = blockIdx.x * blockDim.x + threadIdx.x;
    if (b < B_) {
        int pos = atomicAdd(&hist[len[b]], 1);
        rowmap[pos] = b;
    }
}

// ---------------- prep: transpose + permute weights ----------------
__global__ void k_prep_w(const float* __restrict__ Wih0, const float* __restrict__ Whh0,
                         const float* __restrict__ bih0, const float* __restrict__ bhh0,
                         const float* __restrict__ Wih1, const float* __restrict__ Whh1,
                         const float* __restrict__ bih1, const float* __restrict__ bhh1,
                         float* __restrict__ wt0, float* __restrict__ wt1,
                         float* __restrict__ bb0, float* __restrict__ bb1) {
    int idx = blockIdx.x * blockDim.x + threadIdx.x;
    if (idx < K0_ * NCOL) {
        int k = idx / NCOL, p = idx - k * NCOL;
        int cell = (p < 200) ? 2 * (p >> 2) : 2 * ((p - 200) >> 2) + 1;
        int gate = (p < 200) ? (p & 3) : ((p - 200) & 3);
        int row  = gate * 100 + cell;
        wt0[idx] = (k < 100) ? Whh0[row * H_ + k] : Wih0[row * F_ + (k - 100)];
    }
    if (idx < K1_ * NCOL) {
        int k = idx / NCOL, p = idx - k * NCOL;
        int cell = (p < 200) ? 2 * (p >> 2) : 2 * ((p - 200) >> 2) + 1;
        int gate = (p < 200) ? (p & 3) : ((p - 200) & 3);
        int row  = gate * 100 + cell;
        wt1[idx] = (k < 100) ? Wih1[row * H_ + k] : Whh1[row * H_ + (k - 100)];
    }
    if (idx < NCOL) {
        int p = idx;
        int cell = (p < 200) ? 2 * (p >> 2) : 2 * ((p - 200) >> 2) + 1;
        int gate = (p < 200) ? (p & 3) : ((p - 200) & 3);
        int row  = gate * 100 + cell;
        bb0[idx] = bih0[row] + bhh0[row];
        bb1[idx] = bih1[row] + bhh1[row];
    }
}

// ---------------- staging helpers (static reg indexing only!) ----------------
template <int NK>
__device__ __forceinline__ void prefetchChunk(const float* __restrict__ g, int tid, float4* st) {
    constexpr int TOT = NK * 100;             // float4 count (NK*400 floats /4)
    const float4* g4 = reinterpret_cast<const float4*>(g);
#pragma unroll
    for (int n = 0; n < (TOT + 255) / 256; ++n) {
        int i = tid + n * 256;
        if (i < TOT) st[n] = g4[i];
    }
}
template <int NK>
__device__ __forceinline__ void storeChunk(float* __restrict__ d, int tid, const float4* st) {
    constexpr int TOT = NK * 100;
    float4* d4 = reinterpret_cast<float4*>(d);
#pragma unroll
    for (int n = 0; n < (TOT + 255) / 256; ++n) {
        int i = tid + n * 256;
        if (i < TOT) d4[i] = st[n];
    }
}

// ---------------- GEMM chunk: acc[4][8] += h[4][NK] * w[NK][8-permuted] ----
template <int NK, int HS>
__device__ __forceinline__ void computeChunk(const float* __restrict__ hb,
                                             const float* __restrict__ wb,
                                             int jt, float acc[4][8]) {
#pragma unroll
    for (int kk = 0; kk < NK; kk += 4) {
        float hv[4][4];
#pragma unroll
        for (int r = 0; r < 4; ++r) {
            float4 h4 = *reinterpret_cast<const float4*>(hb + r * HS + kk);
            hv[r][0] = h4.x; hv[r][1] = h4.y; hv[r][2] = h4.z; hv[r][3] = h4.w;
        }
#pragma unroll
        for (int q = 0; q < 4; ++q) {
            float4 wa = *reinterpret_cast<const float4*>(wb + (kk + q) * NCOL + 4 * jt);
            float4 wo = *reinterpret_cast<const float4*>(wb + (kk + q) * NCOL + 200 + 4 * jt);
#pragma unroll
            for (int r = 0; r < 4; ++r) {
                float h = hv[r][q];
                acc[r][0] = fmaf(h, wa.x, acc[r][0]);
                acc[r][1] = fmaf(h, wa.y, acc[r][1]);
                acc[r][2] = fmaf(h, wa.z, acc[r][2]);
                acc[r][3] = fmaf(h, wa.w, acc[r][3]);
                acc[r][4] = fmaf(h, wo.x, acc[r][4]);
                acc[r][5] = fmaf(h, wo.y, acc[r][5]);
                acc[r][6] = fmaf(h, wo.z, acc[r][6]);
                acc[r][7] = fmaf(h, wo.w, acc[r][7]);
            }
        }
    }
}

// ---------------- main persistent LSTM kernel ----------------
__global__ __launch_bounds__(256) void k_lstm(
    const float* __restrict__ x, const int* __restrict__ lengths,
    const int* __restrict__ rowmap,
    const float* __restrict__ wt0, const float* __restrict__ wt1,
    const float* __restrict__ bb0, const float* __restrict__ bb1,
    const float* __restrict__ Wfc, const float* __restrict__ bfc,
    float* __restrict__ out) {
    __shared__ __align__(16) float wbuf[2][CK * NCOL];   // 2*19200B
    __shared__ __align__(16) float hT0[16][S0];          // 7424B
    __shared__ __align__(16) float hT1[16][S1];          // 12800B
    __shared__ int sRow[16], sLen[16], sTmax;

    const int tid = threadIdx.x;
    const int blk = blockIdx.x;

    if (tid < 16) {
        int r = rowmap[blk * 16 + tid];
        sRow[tid] = r;
        sLen[tid] = lengths[r];
    }
    for (int i = tid; i < 16 * S0; i += 256) (&hT0[0][0])[i] = 0.0f;
    for (int i = tid; i < 16 * S1; i += 256) (&hT1[0][0])[i] = 0.0f;
    __syncthreads();
    if (tid == 0) {
        int m = 0;
        for (int i = 0; i < 16; i++) m = max(m, sLen[i]);
        sTmax = m;
    }
    __syncthreads();
    const int Tmax = sTmax;

    const bool act = (tid < 200);
    const int rg = tid / 50, jt = tid % 50;
    const int r0 = 4 * rg;

    float c0[4][2] = {}, c1[4][2] = {};
    float b0v[8], b1v[8];
    if (act) {
#pragma unroll
        for (int q = 0; q < 4; ++q) {
            b0v[q]     = bb0[4 * jt + q];
            b0v[4 + q] = bb0[200 + 4 * jt + q];
            b1v[q]     = bb1[4 * jt + q];
            b1v[4 + q] = bb1[200 + 4 * jt + q];
        }
    }

    const int xr = tid / 13, xk = tid - 13 * xr;
    const bool xact = (tid < 208);
    const float* xptr = x + (xact ? ((size_t)sRow[xr] * (T_ * F_) + xk) : 0);

    float4 stash[5];
    prefetchChunk<12>(wt0, tid, stash);   // G0 chunk0

    for (int t = 0; t < Tmax; ++t) {
        // x_t -> hT0[.][100..112] (read only in G0 chunks covering k>=96; barriers below cover)
        if (xact) hT0[xr][100 + xk] = xptr[(size_t)t * F_];

        // ---------------- layer-0 GEMM: z0 = [h0,x] * wt0 ----------------
        float A0[4][8];
        if (act) {
#pragma unroll
            for (int r = 0; r < 4; ++r)
#pragma unroll
                for (int q = 0; q < 8; ++q) A0[r][q] = b0v[q];
        }
#pragma unroll 1
        for (int c = 0; c < 9; ++c) {
            storeChunk<12>(wbuf[c & 1], tid, stash);
            if (c < 8) prefetchChunk<12>(wt0 + (c + 1) * (CK * NCOL), tid, stash);
            else       prefetchChunk<5>(wt0 + 9 * (CK * NCOL), tid, stash);
            __syncthreads();
            if (act) computeChunk<12, S0>(&hT0[r0][c * CK], wbuf[c & 1], jt, A0);
        }
        storeChunk<5>(wbuf[1], tid, stash);
        prefetchChunk<12>(wt1, tid, stash);
        __syncthreads();
        if (act) computeChunk<5, S0>(&hT0[r0][108], wbuf[1], jt, A0);
        __syncthreads();   // all G0 reads of hT0 done before h0 writes

        // ---------------- layer-0 update ----------------
        if (act) {
#pragma unroll
            for (int r = 0; r < 4; ++r) {
                const int rr = r0 + r;
                if (t < sLen[rr]) {
#pragma unroll
                    for (int jj = 0; jj < 2; ++jj) {
                        const int base = jj ? 4 : 0;
                        float zi = A0[r][base + 0], zf = A0[r][base + 1];
                        float zg = A0[r][base + 2], zo = A0[r][base + 3];
                        float cn = sigmoid_f(zf) * c0[r][jj] + sigmoid_f(zi) * tanh_f(zg);
                        float hn = sigmoid_f(zo) * tanh_f(cn);
                        c0[r][jj] = cn;
                        hT0[rr][2 * jt + jj] = hn;   // h0 for next step
                        hT1[rr][2 * jt + jj] = hn;   // h0n into layer1
                    }
                }
            }
        }

        // ---------------- layer-1 GEMM: z1 = [h0n,h1] * wt1 ----------------
        float A1[4][8];
        if (act) {
#pragma unroll
            for (int r = 0; r < 4; ++r)
#pragma unroll
                for (int q = 0; q < 8; ++q) A1[r][q] = b1v[q];
        }
#pragma unroll 1
        for (int c = 0; c < 16; ++c) {
            storeChunk<12>(wbuf[c & 1], tid, stash);
            if (c < 15) prefetchChunk<12>(wt1 + (c + 1) * (CK * NCOL), tid, stash);
            else        prefetchChunk<8>(wt1 + 16 * (CK * NCOL), tid, stash);
            __syncthreads();
            if (act) computeChunk<12, S1>(&hT1[r0][c * CK], wbuf[c & 1], jt, A1);
        }
        storeChunk<8>(wbuf[0], tid, stash);
        prefetchChunk<12>(wt0, tid, stash);   // next step's G0 chunk0
        __syncthreads();
        if (act) computeChunk<8, S1>(&hT1[r0][192], wbuf[0], jt, A1);
        __syncthreads();   // all G1 reads of hT1 done before h writes

        // ---------------- layer-1 update ----------------
        if (act) {
#pragma unroll
            for (int r = 0; r < 4; ++r) {
                const int rr = r0 + r;
                if (t < sLen[rr]) {
#pragma unroll
                    for (int jj = 0; jj < 2; ++jj) {
                        const int base = jj ? 4 : 0;
                        float zi = A1[r][base + 0], zf = A1[r][base + 1];
                        float zg = A1[r][base + 2], zo = A1[r][base + 3];
                        float cn = sigmoid_f(zf) * c1[r][jj] + sigmoid_f(zi) * tanh_f(zg);
                        float hn = sigmoid_f(zo) * tanh_f(cn);
                        c1[r][jj] = cn;
                        hT1[rr][100 + 2 * jt + jj] = hn;  // frozen after t=len-1
                    }
                }
            }
        }
    }
    __syncthreads();

    if (tid < 16) {
        float s = 0.0f;
        for (int j = 0; j < H_; ++j) s = fmaf(Wfc[j], hT1[tid][100 + j], s);
        out[sRow[tid]] = s + bfc[0];
    }
}

// ---------------- launch ----------------
extern "C" void kernel_launch(void* const* d_in, const int* in_sizes, int n_in,
                              void* d_out, int out_size, void* d_ws, size_t ws_size,
                              hipStream_t stream) {
    const float* x    = (const float*)d_in[0];
    const int*   len  = (const int*)d_in[1];
    const float* Wih0 = (const float*)d_in[2];
    const float* Whh0 = (const float*)d_in[3];
    const float* bih0 = (const float*)d_in[4];
    const float* bhh0 = (const float*)d_in[5];
    const float* Wih1 = (const float*)d_in[6];
    const float* Whh1 = (const float*)d_in[7];
    const float* bih1 = (const float*)d_in[8];
    const float* bhh1 = (const float*)d_in[9];
    const float* Wfc  = (const float*)d_in[10];
    const float* bfc  = (const float*)d_in[11];
    float* out = (float*)d_out;

    char* ws = (char*)d_ws;
    int*   hist   = (int*)(ws + O_HIST);
    int*   rowmap = (int*)(ws + O_ROWMAP);
    float* wt0    = (float*)(ws + O_WT0);
    float* wt1    = (float*)(ws + O_WT1);
    float* bb0    = (float*)(ws + O_B0);
    float* bb1    = (float*)(ws + O_B1);

    hipMemsetAsync(hist, 0, 512, stream);
    k_hist<<<16, 256, 0, stream>>>(len, hist);
    k_scan<<<1, 64, 0, stream>>>(hist);
    k_scatter<<<16, 256, 0, stream>>>(len, hist, rowmap);
    k_prep_w<<<(K1_ * NCOL + 255) / 256, 256, 0, stream>>>(Wih0, Whh0, bih0, bhh0,
                                                           Wih1, Whh1, bih1, bhh1,
                                                           wt0, wt1, bb0, bb1);
    k_lstm<<<256, 256, 0, stream>>>(x, len, rowmap, wt0, wt1, bb0, bb1, Wfc, bfc, out);
}

// Round 3
// 1652.454 us; speedup vs baseline: 3.0262x; 3.0262x over previous
//
#include <hip/hip_runtime.h>
#include <math.h>

// Problem constants (B=4096, T=100, F=13, H=100)
#define B_    4096
#define T_    100
#define F_    13
#define H_    100

typedef short bf16x8 __attribute__((ext_vector_type(8)));
typedef float f32x4  __attribute__((ext_vector_type(4)));

// ---- ws layout (bytes), total 651,264 ----
#define O_HIST   0u        // 512
#define O_ROWMAP 512u      // 4096*4
#define O_BIAS0  16896u    // 448*4
#define O_BIAS1  18688u    // 448*4
#define O_B0     20480u    // 4kt * 28672 u16 * 2B = 229376
#define O_B1     249856u   // 7kt * 28672 u16 * 2B = 401408 -> 651264

// B-fragment array layout (u16 units), per layer:
//   idx = (((kt*4 + g)*7 + ct)*2 + pass)*512 + lane*8 + j
// where lane's frag element j holds W_pass[k = kt*32 + (lane>>4)*8 + j]
//                                  [col = g*112 + ct*16 + (lane&15)]
// (cols are gate-major with H padded 100->112; pad cols/k are zero)

__device__ __forceinline__ float sigmoid_f(float v) {
    return 1.0f / (1.0f + __expf(-v));
}
__device__ __forceinline__ float tanh_f(float v) {
    float e = __expf(2.0f * v);
    return 1.0f - 2.0f / (e + 1.0f);
}
// fp32 -> bf16 hi (truncate) + lo (RNE of remainder): hi+lo ~ 2^-17 rel err
__device__ __forceinline__ void split_bf16(float v, unsigned short& hi, unsigned short& lo) {
    unsigned u = __float_as_uint(v);
    hi = (unsigned short)(u >> 16);
    float hf = __uint_as_float(u & 0xFFFF0000u);
    float rem = v - hf;
    unsigned r = __float_as_uint(rem);
    unsigned rnd = r + 0x7FFFu + ((r >> 16) & 1u);
    lo = (unsigned short)(rnd >> 16);
}
__device__ __forceinline__ float bf16_to_f(unsigned short b) {
    return __uint_as_float(((unsigned)b) << 16);
}

// ---------------- prep: counting sort of rows by length ----------------
__global__ void k_hist(const int* __restrict__ len, int* __restrict__ hist) {
    int b = blockIdx.x * blockDim.x + threadIdx.x;
    if (b < B_) atomicAdd(&hist[len[b]], 1);
}
__global__ void k_scan(int* __restrict__ hist) {
    if (threadIdx.x == 0 && blockIdx.x == 0) {
        int acc = 0;
        for (int l = 0; l <= 100; ++l) { int c = hist[l]; hist[l] = acc; acc += c; }
    }
}
__global__ void k_scatter(const int* __restrict__ len, int* __restrict__ hist,
                          int* __restrict__ rowmap) {
    int b = blockIdx.x * blockDim.x + threadIdx.x;
    if (b < B_) {
        int pos = atomicAdd(&hist[len[b]], 1);
        rowmap[pos] = b;
    }
}

// ---------------- prep: biases (gate-major, padded) ----------------
__global__ void k_prep_bias(const float* __restrict__ bih0, const float* __restrict__ bhh0,
                            const float* __restrict__ bih1, const float* __restrict__ bhh1,
                            float* __restrict__ bias0, float* __restrict__ bias1) {
    int idx = blockIdx.x * blockDim.x + threadIdx.x;
    if (idx < 448) {
        int g = idx / 112, cell = idx % 112;
        float v0 = 0.f, v1 = 0.f;
        if (cell < 100) {
            int row = g * 100 + cell;
            v0 = bih0[row] + bhh0[row];
            v1 = bih1[row] + bhh1[row];
        }
        bias0[idx] = v0; bias1[idx] = v1;
    }
}

// ---------------- prep: weights into B-fragment order, bf16 hi/lo ----------
// Layer0 A-k: k<100 -> h0 (Whh0), 100..112 -> x (Wih0), >=113 -> 0
// Layer1 A-k: k<100 -> h0n (Wih1), 100..199 -> h1 (Whh1), >=200 -> 0
__global__ void k_prep_b(const float* __restrict__ Wih0, const float* __restrict__ Whh0,
                         const float* __restrict__ Wih1, const float* __restrict__ Whh1,
                         unsigned short* __restrict__ B0, unsigned short* __restrict__ B1) {
    const int PER_KT = 4 * 7 * 2 * 512;  // 28672 u16 per K-tile
    int idx = blockIdx.x * blockDim.x + threadIdx.x;
    if (idx >= 7 * PER_KT) return;
    int kt = idx / PER_KT;
    int s  = idx % PER_KT;
    int g  = s / 7168;
    int s2 = s % 7168;
    int ct = s2 / 1024;
    int s3 = s2 % 1024;
    int pass = s3 / 512;
    int e  = s3 % 512;
    int lane = e >> 3, j = e & 7;
    int n = lane & 15, q = lane >> 4;
    int k = kt * 32 + q * 8 + j;
    int cell = ct * 16 + n;

    unsigned short hi, lo;
    {   // layer 1
        float w = 0.f;
        if (cell < 100) {
            int row = g * 100 + cell;
            if (k < 100)      w = Wih1[row * 100 + k];
            else if (k < 200) w = Whh1[row * 100 + (k - 100)];
        }
        split_bf16(w, hi, lo);
        B1[idx] = pass ? lo : hi;
    }
    if (kt < 4) {  // layer 0
        float w = 0.f;
        if (cell < 100) {
            int row = g * 100 + cell;
            if (k < 100)      w = Whh0[row * 100 + k];
            else if (k < 113) w = Wih0[row * 13 + (k - 100)];
        }
        split_bf16(w, hi, lo);
        B0[idx] = pass ? lo : hi;
    }
}

// ---------------- main persistent MFMA LSTM ----------------
// 128 blocks x 32 rows. Waves 0..6: cell-tile ct (cells 16ct..16ct+15), all 4
// gates, both M-tiles. Wave 7: x prefetch. A-state in LDS as bf16 hi/lo in
// A-fragment layout; B-frags read directly from global (pre-permuted, L2-hot).
__global__ __launch_bounds__(512, 2) void k_lstm(
    const float* __restrict__ x, const int* __restrict__ lengths,
    const int* __restrict__ rowmap,
    const unsigned short* __restrict__ B0, const unsigned short* __restrict__ B1,
    const float* __restrict__ bias0, const float* __restrict__ bias1,
    const float* __restrict__ Wfc, const float* __restrict__ bfc,
    float* __restrict__ out)
{
    // strides padded (+8 u16) so frag reads are 2-way-conflict max (free)
    __shared__ __align__(16) unsigned short Ah0[32 * 136];
    __shared__ __align__(16) unsigned short Al0[32 * 136];
    __shared__ __align__(16) unsigned short Ah1[32 * 232];
    __shared__ __align__(16) unsigned short Al1[32 * 232];
    __shared__ int sRow[32], sLen[32], sTmax;

    const int tid = threadIdx.x;
    const int wv = tid >> 6, lane = tid & 63;

    if (tid < 32) {
        int r = rowmap[blockIdx.x * 32 + tid];
        sRow[tid] = r; sLen[tid] = lengths[r];
    }
    for (int i = tid; i < 32 * 136; i += 512) { Ah0[i] = 0; Al0[i] = 0; }
    for (int i = tid; i < 32 * 232; i += 512) { Ah1[i] = 0; Al1[i] = 0; }
    __syncthreads();
    if (tid == 0) { int m = 0; for (int i = 0; i < 32; ++i) m = max(m, sLen[i]); sTmax = m; }

    // ---- per-wave setup ----
    const int ct = wv, n = lane & 15, q = lane >> 4;
    const int cell = ct * 16 + n;

    float b0v[4], b1v[4];
    int   lenR[8];
    float c0[8], c1[8];
    int offA0[2], offA1[2];
    if (wv < 7) {
#pragma unroll
        for (int g = 0; g < 4; ++g) {
            b0v[g] = bias0[g * 112 + cell];
            b1v[g] = bias1[g * 112 + cell];
        }
#pragma unroll
        for (int mt = 0; mt < 2; ++mt) {
            offA0[mt] = (mt * 16 + n) * 136 + q * 8;
            offA1[mt] = (mt * 16 + n) * 232 + q * 8;
#pragma unroll
            for (int r = 0; r < 4; ++r) {
                lenR[mt * 4 + r] = sLen[mt * 16 + q * 4 + r];
                c0[mt * 4 + r] = 0.f; c1[mt * 4 + r] = 0.f;
            }
        }
    }

    // wave 7: x loader (32 rows x 13 feats = 416 slots, 7 per lane)
    int xvalid[7]; size_t xg[7]; int xa[7]; float xv[7];
    if (wv == 7) {
#pragma unroll
        for (int i = 0; i < 7; ++i) {
            int e = i * 64 + lane;
            xvalid[i] = (e < 416);
            int r = xvalid[i] ? (e / 13) : 0;
            int f = xvalid[i] ? (e - 13 * r) : 0;
            xg[i] = (size_t)sRow[r] * (T_ * F_) + f;
            xa[i] = r * 136 + 100 + f;
            xv[i] = xvalid[i] ? x[xg[i]] : 0.f;   // t = 0
        }
    }
    __syncthreads();           // sTmax + sRow-dependent setup done
    const int Tmax = sTmax;
    if (wv == 7) {             // write x_0 (visible after loop's barrier 1)
#pragma unroll
        for (int i = 0; i < 7; ++i) if (xvalid[i]) {
            unsigned short hi, lo; split_bf16(xv[i], hi, lo);
            Ah0[xa[i]] = hi; Al0[xa[i]] = lo;
        }
    }

    for (int t = 0; t < Tmax; ++t) {
        __syncthreads();   // (1) A0 current: x_t + h0(t-1)
        float hreg[8];
        if (wv < 7) {
            // ---------- layer-0 GEMM ----------
            f32x4 P[2][4], Q[2][4];
#pragma unroll
            for (int mt = 0; mt < 2; ++mt)
#pragma unroll
                for (int g = 0; g < 4; ++g) {
                    P[mt][g] = (f32x4){b0v[g], b0v[g], b0v[g], b0v[g]};
                    Q[mt][g] = (f32x4){0.f, 0.f, 0.f, 0.f};
                }
#pragma unroll
            for (int kt = 0; kt < 4; ++kt) {
                bf16x8 ah[2], al[2];
#pragma unroll
                for (int mt = 0; mt < 2; ++mt) {
                    ah[mt] = *(const bf16x8*)&Ah0[offA0[mt] + kt * 32];
                    al[mt] = *(const bf16x8*)&Al0[offA0[mt] + kt * 32];
                }
#pragma unroll
                for (int g = 0; g < 4; ++g) {
                    size_t base = ((size_t)((kt * 4 + g) * 7 + ct)) * 1024 + lane * 8;
                    bf16x8 bh = *(const bf16x8*)&B0[base];
                    bf16x8 bl = *(const bf16x8*)&B0[base + 512];
#pragma unroll
                    for (int mt = 0; mt < 2; ++mt) {
                        P[mt][g] = __builtin_amdgcn_mfma_f32_16x16x32_bf16(ah[mt], bh, P[mt][g], 0, 0, 0);
                        Q[mt][g] = __builtin_amdgcn_mfma_f32_16x16x32_bf16(al[mt], bh, Q[mt][g], 0, 0, 0);
                        Q[mt][g] = __builtin_amdgcn_mfma_f32_16x16x32_bf16(ah[mt], bl, Q[mt][g], 0, 0, 0);
                    }
                }
            }
            // ---------- layer-0 pointwise (all in-lane) ----------
#pragma unroll
            for (int mt = 0; mt < 2; ++mt)
#pragma unroll
                for (int r = 0; r < 4; ++r) {
                    float zi = P[mt][0][r] + Q[mt][0][r];
                    float zf = P[mt][1][r] + Q[mt][1][r];
                    float zg = P[mt][2][r] + Q[mt][2][r];
                    float zo = P[mt][3][r] + Q[mt][3][r];
                    float cn = sigmoid_f(zf) * c0[mt * 4 + r] + sigmoid_f(zi) * tanh_f(zg);
                    float hn = sigmoid_f(zo) * tanh_f(cn);
                    if (t < lenR[mt * 4 + r]) c0[mt * 4 + r] = cn;
                    hreg[mt * 4 + r] = hn;
                }
        } else {
            if (t + 1 < Tmax) {
#pragma unroll
                for (int i = 0; i < 7; ++i)
                    if (xvalid[i]) xv[i] = x[xg[i] + (size_t)(t + 1) * F_];
            }
        }
        __syncthreads();   // (2) all A0 frag reads done
        if (wv < 7) {
            if (cell < 100) {
#pragma unroll
                for (int mt = 0; mt < 2; ++mt)
#pragma unroll
                    for (int r = 0; r < 4; ++r) {
                        if (t < lenR[mt * 4 + r]) {
                            int m = mt * 16 + q * 4 + r;
                            unsigned short hi, lo; split_bf16(hreg[mt * 4 + r], hi, lo);
                            Ah0[m * 136 + cell] = hi; Al0[m * 136 + cell] = lo;
                            Ah1[m * 232 + cell] = hi; Al1[m * 232 + cell] = lo;
                        }
                    }
            }
        } else {
            if (t + 1 < Tmax) {
#pragma unroll
                for (int i = 0; i < 7; ++i) if (xvalid[i]) {
                    unsigned short hi, lo; split_bf16(xv[i], hi, lo);
                    Ah0[xa[i]] = hi; Al0[xa[i]] = lo;
                }
            }
        }
        __syncthreads();   // (3) A1 current: h0n + h1(t-1)
        if (wv < 7) {
            // ---------- layer-1 GEMM ----------
            f32x4 P[2][4], Q[2][4];
#pragma unroll
            for (int mt = 0; mt < 2; ++mt)
#pragma unroll
                for (int g = 0; g < 4; ++g) {
                    P[mt][g] = (f32x4){b1v[g], b1v[g], b1v[g], b1v[g]};
                    Q[mt][g] = (f32x4){0.f, 0.f, 0.f, 0.f};
                }
#pragma unroll
            for (int kt = 0; kt < 7; ++kt) {
                bf16x8 ah[2], al[2];
#pragma unroll
                for (int mt = 0; mt < 2; ++mt) {
                    ah[mt] = *(const bf16x8*)&Ah1[offA1[mt] + kt * 32];
                    al[mt] = *(const bf16x8*)&Al1[offA1[mt] + kt * 32];
                }
#pragma unroll
                for (int g = 0; g < 4; ++g) {
                    size_t base = ((size_t)((kt * 4 + g) * 7 + ct)) * 1024 + lane * 8;
                    bf16x8 bh = *(const bf16x8*)&B1[base];
                    bf16x8 bl = *(const bf16x8*)&B1[base + 512];
#pragma unroll
                    for (int mt = 0; mt < 2; ++mt) {
                        P[mt][g] = __builtin_amdgcn_mfma_f32_16x16x32_bf16(ah[mt], bh, P[mt][g], 0, 0, 0);
                        Q[mt][g] = __builtin_amdgcn_mfma_f32_16x16x32_bf16(al[mt], bh, Q[mt][g], 0, 0, 0);
                        Q[mt][g] = __builtin_amdgcn_mfma_f32_16x16x32_bf16(ah[mt], bl, Q[mt][g], 0, 0, 0);
                    }
                }
            }
            // ---------- layer-1 pointwise ----------
#pragma unroll
            for (int mt = 0; mt < 2; ++mt)
#pragma unroll
                for (int r = 0; r < 4; ++r) {
                    float zi = P[mt][0][r] + Q[mt][0][r];
                    float zf = P[mt][1][r] + Q[mt][1][r];
                    float zg = P[mt][2][r] + Q[mt][2][r];
                    float zo = P[mt][3][r] + Q[mt][3][r];
                    float cn = sigmoid_f(zf) * c1[mt * 4 + r] + sigmoid_f(zi) * tanh_f(zg);
                    float hn = sigmoid_f(zo) * tanh_f(cn);
                    if (t < lenR[mt * 4 + r]) c1[mt * 4 + r] = cn;
                    hreg[mt * 4 + r] = hn;
                }
        }
        __syncthreads();   // (4) all A1 frag reads done
        if (wv < 7 && cell < 100) {
#pragma unroll
            for (int mt = 0; mt < 2; ++mt)
#pragma unroll
                for (int r = 0; r < 4; ++r) {
                    if (t < lenR[mt * 4 + r]) {
                        int m = mt * 16 + q * 4 + r;
                        unsigned short hi, lo; split_bf16(hreg[mt * 4 + r], hi, lo);
                        Ah1[m * 232 + 100 + cell] = hi; Al1[m * 232 + 100 + cell] = lo;
                    }
                }
        }
    }
    __syncthreads();

    // final: out[b] = W_fc . h1 + b_fc  (h1 = hi+lo, frozen at len-1)
    if (tid < 32) {
        float s = bfc[0];
        for (int j = 0; j < 100; ++j) {
            float h = bf16_to_f(Ah1[tid * 232 + 100 + j]) + bf16_to_f(Al1[tid * 232 + 100 + j]);
            s = fmaf(Wfc[j], h, s);
        }
        out[sRow[tid]] = s;
    }
}

// ---------------- launch ----------------
extern "C" void kernel_launch(void* const* d_in, const int* in_sizes, int n_in,
                              void* d_out, int out_size, void* d_ws, size_t ws_size,
                              hipStream_t stream) {
    const float* x    = (const float*)d_in[0];
    const int*   len  = (const int*)d_in[1];
    const float* Wih0 = (const float*)d_in[2];
    const float* Whh0 = (const float*)d_in[3];
    const float* bih0 = (const float*)d_in[4];
    const float* bhh0 = (const float*)d_in[5];
    const float* Wih1 = (const float*)d_in[6];
    const float* Whh1 = (const float*)d_in[7];
    const float* bih1 = (const float*)d_in[8];
    const float* bhh1 = (const float*)d_in[9];
    const float* Wfc  = (const float*)d_in[10];
    const float* bfc  = (const float*)d_in[11];
    float* out = (float*)d_out;

    char* ws = (char*)d_ws;   // uses 651,264 bytes
    int*            hist   = (int*)(ws + O_HIST);
    int*            rowmap = (int*)(ws + O_ROWMAP);
    float*          bias0  = (float*)(ws + O_BIAS0);
    float*          bias1  = (float*)(ws + O_BIAS1);
    unsigned short* B0     = (unsigned short*)(ws + O_B0);
    unsigned short* B1     = (unsigned short*)(ws + O_B1);

    hipMemsetAsync(hist, 0, 512, stream);
    k_hist<<<16, 256, 0, stream>>>(len, hist);
    k_scan<<<1, 64, 0, stream>>>(hist);
    k_scatter<<<16, 256, 0, stream>>>(len, hist, rowmap);
    k_prep_bias<<<2, 256, 0, stream>>>(bih0, bhh0, bih1, bhh1, bias0, bias1);
    k_prep_b<<<(7 * 28672 + 255) / 256, 256, 0, stream>>>(Wih0, Whh0, Wih1, Whh1, B0, B1);
    k_lstm<<<128, 512, 0, stream>>>(x, len, rowmap, B0, B1, bias0, bias1, Wfc, bfc, out);
}